// Round 1
// baseline (1992.136 us; speedup 1.0000x reference)
//
#include <hip/hip_runtime.h>
#include <math.h>

// ---------------- problem constants ----------------
#define T_TOK 2048
#define HD    1024
#define FD    4096
#define FH    2048     // F/2
#define HG    8192     // H * NUM_GRIDS
#define FHG   16384    // (F/2) * NUM_GRIDS
#define MAXR  4608     // max padded rows per region (2*T + 4*64 slack)

typedef __bf16 bf16x8_t __attribute__((ext_vector_type(8)));
typedef float  f32x4_t  __attribute__((ext_vector_type(4)));

// ---------------- workspace layout (bytes) ----------------
#define WS_CNT   0           // int[8]   selections per expert
#define WS_FILL  64          // int[8]   fill cursors
#define WS_OFFS  128         // int[16]  [0..7] seg start row (region-local), [8..15] padded count
#define WS_SEL   256         // int[T][2]
#define WS_SELW  16640       // float[T][2]
#define WS_TL    33024       // int[2][MAXR]    token index per row (region 0=MLP, 1=KAN)
#define WS_TW    69888       // float[2][MAXR]  combine weight per row
#define WS_CTRL_END 106752
#define WS_XB    107520      // ushort[T][HD]       x in bf16
#define WS_B1    4301824     // ushort[T][HG]       rswaf(x) in bf16
#define WS_H     37856256    // ushort[MAXR][FD]    gelu(fc1) in bf16
#define WS_K1    75604992    // ushort[MAXR][FH]    spline1 out in bf16
// total ~94.5 MB

// ---------------- helpers ----------------
__device__ __forceinline__ unsigned short f2bf(float f) {
    unsigned int u = __float_as_uint(f);
    u += 0x7fffu + ((u >> 16) & 1u);   // round-to-nearest-even
    return (unsigned short)(u >> 16);
}
__device__ __forceinline__ float bf2f(unsigned short h) {
    return __uint_as_float(((unsigned int)h) << 16);
}
__device__ __forceinline__ void rswaf8(float v, unsigned short* o) {
    #pragma unroll
    for (int g = 0; g < 8; g++) {
        float d  = (v - (-1.2f + 0.2f * (float)g)) * 0.5f;
        float th = tanhf(d);
        o[g] = f2bf(1.0f - th * th);
    }
}

// ---------------- router: logits -> softmax -> top2 -> weights ----------------
__global__ __launch_bounds__(256) void router_k(
    const float* __restrict__ x, const float* __restrict__ gw,
    int* __restrict__ cnt, int* __restrict__ sel, float* __restrict__ selw)
{
    const int t = blockIdx.x, tid = threadIdx.x;
    __shared__ float red[8][256];
    float p[8] = {0,0,0,0,0,0,0,0};
    for (int h = tid; h < HD; h += 256) {
        float xv = x[(size_t)t * HD + h];
        #pragma unroll
        for (int e = 0; e < 8; e++) p[e] += xv * gw[e * HD + h];
    }
    #pragma unroll
    for (int e = 0; e < 8; e++) red[e][tid] = p[e];
    __syncthreads();
    for (int s = 128; s > 0; s >>= 1) {
        if (tid < s) {
            #pragma unroll
            for (int e = 0; e < 8; e++) red[e][tid] += red[e][tid + s];
        }
        __syncthreads();
    }
    if (tid == 0) {
        float l[8];
        #pragma unroll
        for (int e = 0; e < 8; e++) l[e] = red[e][0];
        float mx = l[0];
        #pragma unroll
        for (int e = 1; e < 8; e++) mx = fmaxf(mx, l[e]);
        float pe[8];
        #pragma unroll
        for (int e = 0; e < 8; e++) pe[e] = expf(l[e] - mx);
        // top-2 (strict > keeps lowest index on ties, matching lax.top_k)
        int i1 = 0; float v1 = pe[0];
        #pragma unroll
        for (int e = 1; e < 8; e++) if (pe[e] > v1) { v1 = pe[e]; i1 = e; }
        int i2 = -1; float v2 = -1.0f;
        #pragma unroll
        for (int e = 0; e < 8; e++) if (e != i1 && pe[e] > v2) { v2 = pe[e]; i2 = e; }
        float wsum = v1 + v2;
        sel[t * 2] = i1;  sel[t * 2 + 1] = i2;
        selw[t * 2] = v1 / wsum;  selw[t * 2 + 1] = v2 / wsum;
        atomicAdd(&cnt[i1], 1);  atomicAdd(&cnt[i2], 1);
    }
}

// ---------------- segment offsets (single thread) ----------------
__global__ void offs_k(const int* __restrict__ cnt, int* __restrict__ offs) {
    if (threadIdx.x == 0 && blockIdx.x == 0) {
        int mo = 0;
        for (int e = 0; e < 4; e++) { offs[e] = mo; int pc = (cnt[e] + 63) & ~63; offs[8 + e] = pc; mo += pc; }
        int ko = 0;
        for (int e = 4; e < 8; e++) { offs[e] = ko; int pc = (cnt[e] + 63) & ~63; offs[8 + e] = pc; ko += pc; }
    }
}

// ---------------- build compacted token lists ----------------
__global__ __launch_bounds__(256) void build_k(
    const int* __restrict__ sel, const float* __restrict__ selw,
    const int* __restrict__ offs, int* __restrict__ fill,
    int* __restrict__ tl, float* __restrict__ tw)
{
    int t = blockIdx.x * blockDim.x + threadIdx.x;
    if (t >= T_TOK) return;
    for (int s = 0; s < 2; s++) {
        int e = sel[t * 2 + s];
        float w = selw[t * 2 + s];
        int pos = atomicAdd(&fill[e], 1);
        int r = e >> 2;
        int row = offs[e] + pos;
        tl[r * MAXR + row] = t;
        tw[r * MAXR + row] = w;
    }
}

// ---------------- xb (bf16 cast) + b1 (rswaf basis) precompute ----------------
__global__ __launch_bounds__(256) void basis_k(
    const float* __restrict__ x, unsigned short* __restrict__ xb,
    unsigned short* __restrict__ b1)
{
    int i = blockIdx.x * 256 + threadIdx.x;   // over T*HD
    float v = x[i];
    xb[i] = f2bf(v);
    union { unsigned short u[8]; uint4 q; } o;
    rswaf8(v, o.u);
    *(uint4*)(b1 + (size_t)i * 8) = o.q;
}

// ================= GEMM kernels: 64x64 tile, BK=32, 4 waves (2x2 of 16x16x32 mfma each) =================
// LDS layout: [64 rows][40 shorts] (pad 8 -> 2-way bank alias only, free)

#define GEMM_PROLOG(PCNT_IDX, SEG_IDX)                                   \
    const int e = blockIdx.z;                                            \
    const int pcnt = offs[PCNT_IDX];                                     \
    const int mt = blockIdx.y;                                           \
    if (mt * 64 >= pcnt) return;                                         \
    const int seg = offs[SEG_IDX];                                       \
    const int n0 = blockIdx.x * 64;                                      \
    const int tid = threadIdx.x;                                         \
    __shared__ __align__(16) unsigned short As[64 * 40];                 \
    __shared__ __align__(16) unsigned short Bs[64 * 40];                 \
    const int srow = tid >> 2, sc = tid & 3;                             \
    f32x4_t acc[2][2] = {{{0,0,0,0},{0,0,0,0}},{{0,0,0,0},{0,0,0,0}}};   \
    const int lane = tid & 63, wv = tid >> 6;                            \
    const int wm = (wv >> 1) * 32, wn = (wv & 1) * 32;                   \
    const int fr = lane & 15, quad = lane >> 4;

#define GEMM_MFMA_STEP                                                                    \
    __syncthreads();                                                                      \
    bf16x8_t a0 = *(const bf16x8_t*)(&As[(wm + fr) * 40 + quad * 8]);                     \
    bf16x8_t a1 = *(const bf16x8_t*)(&As[(wm + 16 + fr) * 40 + quad * 8]);                \
    bf16x8_t b0 = *(const bf16x8_t*)(&Bs[(wn + fr) * 40 + quad * 8]);                     \
    bf16x8_t b1f = *(const bf16x8_t*)(&Bs[(wn + 16 + fr) * 40 + quad * 8]);               \
    acc[0][0] = __builtin_amdgcn_mfma_f32_16x16x32_bf16(a0, b0,  acc[0][0], 0, 0, 0);     \
    acc[0][1] = __builtin_amdgcn_mfma_f32_16x16x32_bf16(a0, b1f, acc[0][1], 0, 0, 0);     \
    acc[1][0] = __builtin_amdgcn_mfma_f32_16x16x32_bf16(a1, b0,  acc[1][0], 0, 0, 0);     \
    acc[1][1] = __builtin_amdgcn_mfma_f32_16x16x32_bf16(a1, b1f, acc[1][1], 0, 0, 0);

#define STAGE_B_F32                                                                      \
    float4 bv0 = *(const float4*)(brow + kt + sc * 8);                                   \
    float4 bv1 = *(const float4*)(brow + kt + sc * 8 + 4);                               \
    union { unsigned short u[8]; uint4 v; } bb;                                          \
    bb.u[0]=f2bf(bv0.x); bb.u[1]=f2bf(bv0.y); bb.u[2]=f2bf(bv0.z); bb.u[3]=f2bf(bv0.w);  \
    bb.u[4]=f2bf(bv1.x); bb.u[5]=f2bf(bv1.y); bb.u[6]=f2bf(bv1.z); bb.u[7]=f2bf(bv1.w);

// ---- fc1: h = gelu(x @ fc1_w^T + b), bf16 A gathered from xb ----
__global__ __launch_bounds__(256) void fc1_k(
    const unsigned short* __restrict__ xb, const float* __restrict__ w,
    const float* __restrict__ bias, const int* __restrict__ tl,
    const int* __restrict__ offs, unsigned short* __restrict__ hbuf)
{
    GEMM_PROLOG(8 + e, e)
    const int tok = tl[seg + mt * 64 + srow];
    const unsigned short* arow = xb + (size_t)tok * HD;
    const float* brow = w + (size_t)e * FD * HD + (size_t)(n0 + srow) * HD;
    for (int kt = 0; kt < HD; kt += 32) {
        uint4 av = *(const uint4*)(arow + kt + sc * 8);
        STAGE_B_F32
        __syncthreads();
        *(uint4*)(&As[srow * 40 + sc * 8]) = av;
        *(uint4*)(&Bs[srow * 40 + sc * 8]) = bb.v;
        GEMM_MFMA_STEP
    }
    #pragma unroll
    for (int i = 0; i < 2; i++)
        #pragma unroll
        for (int j = 0; j < 2; j++)
            #pragma unroll
            for (int r = 0; r < 4; r++) {
                int rl = mt * 64 + wm + i * 16 + quad * 4 + r;
                int col = n0 + wn + j * 16 + fr;
                float v = acc[i][j][r] + bias[e * FD + col];
                float gel = 0.5f * v * (1.0f + erff(v * 0.70710678118654752f));
                hbuf[(size_t)(seg + rl) * FD + col] = f2bf(gel);
            }
}

// ---- fc2: out += wt * (h @ fc2_w^T + b) ----
__global__ __launch_bounds__(256) void fc2_k(
    const unsigned short* __restrict__ hbuf, const float* __restrict__ w,
    const float* __restrict__ bias, const int* __restrict__ tl,
    const float* __restrict__ tw, const int* __restrict__ offs,
    float* __restrict__ out)
{
    GEMM_PROLOG(8 + e, e)
    const unsigned short* arow = hbuf + (size_t)(seg + mt * 64 + srow) * FD;
    const float* brow = w + (size_t)e * HD * FD + (size_t)(n0 + srow) * FD;
    for (int kt = 0; kt < FD; kt += 32) {
        uint4 av = *(const uint4*)(arow + kt + sc * 8);
        STAGE_B_F32
        __syncthreads();
        *(uint4*)(&As[srow * 40 + sc * 8]) = av;
        *(uint4*)(&Bs[srow * 40 + sc * 8]) = bb.v;
        GEMM_MFMA_STEP
    }
    #pragma unroll
    for (int i = 0; i < 2; i++)
        #pragma unroll
        for (int j = 0; j < 2; j++)
            #pragma unroll
            for (int r = 0; r < 4; r++) {
                int rlg = seg + mt * 64 + wm + i * 16 + quad * 4 + r;
                int col = n0 + wn + j * 16 + fr;
                int tok = tl[rlg];
                float wt = tw[rlg];
                float v = acc[i][j][r] + bias[e * HD + col];
                atomicAdd(&out[(size_t)tok * HD + col], wt * v);
            }
}

// ---- sp1: k1 = b1 @ sp1_w^T  (A gathered from precomputed b1) ----
__global__ __launch_bounds__(256) void sp1_k(
    const unsigned short* __restrict__ b1, const float* __restrict__ w,
    const int* __restrict__ tl, const int* __restrict__ offs,
    unsigned short* __restrict__ k1)
{
    GEMM_PROLOG(12 + e, 4 + e)
    const int tok = tl[MAXR + seg + mt * 64 + srow];
    const unsigned short* arow = b1 + (size_t)tok * HG;
    const float* brow = w + (size_t)e * FH * HG + (size_t)(n0 + srow) * HG;
    for (int kt = 0; kt < HG; kt += 32) {
        uint4 av = *(const uint4*)(arow + kt + sc * 8);
        STAGE_B_F32
        __syncthreads();
        *(uint4*)(&As[srow * 40 + sc * 8]) = av;
        *(uint4*)(&Bs[srow * 40 + sc * 8]) = bb.v;
        GEMM_MFMA_STEP
    }
    #pragma unroll
    for (int i = 0; i < 2; i++)
        #pragma unroll
        for (int j = 0; j < 2; j++)
            #pragma unroll
            for (int r = 0; r < 4; r++) {
                int rl = mt * 64 + wm + i * 16 + quad * 4 + r;
                int col = n0 + wn + j * 16 + fr;
                k1[(size_t)(seg + rl) * FH + col] = f2bf(acc[i][j][r]);
            }
}

// ---- sp2: out += wt * (rswaf(k1) @ sp2_w^T), basis expanded during A-staging ----
__global__ __launch_bounds__(256) void sp2_k(
    const unsigned short* __restrict__ k1, const float* __restrict__ w,
    const int* __restrict__ tl, const float* __restrict__ tw,
    const int* __restrict__ offs, float* __restrict__ out)
{
    GEMM_PROLOG(12 + e, 4 + e)
    const unsigned short* k1row = k1 + (size_t)(seg + mt * 64 + srow) * FH;
    const float* brow = w + (size_t)e * HD * FHG + (size_t)(n0 + srow) * FHG;
    for (int kt = 0; kt < FHG; kt += 32) {
        float val = bf2f(k1row[(kt >> 3) + sc]);   // k = f*8+g; this thread covers one f
        union { unsigned short u[8]; uint4 q; } aa;
        rswaf8(val, aa.u);
        STAGE_B_F32
        __syncthreads();
        *(uint4*)(&As[srow * 40 + sc * 8]) = aa.q;
        *(uint4*)(&Bs[srow * 40 + sc * 8]) = bb.v;
        GEMM_MFMA_STEP
    }
    #pragma unroll
    for (int i = 0; i < 2; i++)
        #pragma unroll
        for (int j = 0; j < 2; j++)
            #pragma unroll
            for (int r = 0; r < 4; r++) {
                int rlg = seg + mt * 64 + wm + i * 16 + quad * 4 + r;
                int col = n0 + wn + j * 16 + fr;
                int tok = tl[MAXR + rlg];
                float wt = tw[MAXR + rlg];
                atomicAdd(&out[(size_t)tok * HD + col], wt * acc[i][j][r]);
            }
}

// ---------------- launch ----------------
extern "C" void kernel_launch(void* const* d_in, const int* in_sizes, int n_in,
                              void* d_out, int out_size, void* d_ws, size_t ws_size,
                              hipStream_t stream)
{
    const float* x    = (const float*)d_in[0];
    const float* gw   = (const float*)d_in[1];
    const float* fc1w = (const float*)d_in[2];
    const float* fc1b = (const float*)d_in[3];
    const float* fc2w = (const float*)d_in[4];
    const float* fc2b = (const float*)d_in[5];
    const float* sp1w = (const float*)d_in[6];
    const float* sp2w = (const float*)d_in[7];
    float* out = (float*)d_out;
    char* ws = (char*)d_ws;

    int*   cnt  = (int*)(ws + WS_CNT);
    int*   fill = (int*)(ws + WS_FILL);
    int*   offs = (int*)(ws + WS_OFFS);
    int*   sel  = (int*)(ws + WS_SEL);
    float* selw = (float*)(ws + WS_SELW);
    int*   tl   = (int*)(ws + WS_TL);
    float* tw   = (float*)(ws + WS_TW);
    unsigned short* xb = (unsigned short*)(ws + WS_XB);
    unsigned short* b1 = (unsigned short*)(ws + WS_B1);
    unsigned short* hb = (unsigned short*)(ws + WS_H);
    unsigned short* k1 = (unsigned short*)(ws + WS_K1);

    hipMemsetAsync(ws, 0, WS_CTRL_END, stream);
    hipMemsetAsync(out, 0, (size_t)T_TOK * HD * sizeof(float), stream);

    router_k<<<T_TOK, 256, 0, stream>>>(x, gw, cnt, sel, selw);
    offs_k<<<1, 64, 0, stream>>>(cnt, offs);
    build_k<<<(T_TOK + 255) / 256, 256, 0, stream>>>(sel, selw, offs, fill, tl, tw);
    basis_k<<<(T_TOK * HD) / 256, 256, 0, stream>>>(x, xb, b1);

    fc1_k<<<dim3(FD / 64, 32, 4), 256, 0, stream>>>(xb, fc1w, fc1b, tl, offs, hb);
    fc2_k<<<dim3(HD / 64, 32, 4), 256, 0, stream>>>(hb, fc2w, fc2b, tl, tw, offs, out);
    sp1_k<<<dim3(FH / 64, 32, 4), 256, 0, stream>>>(b1, sp1w, tl, offs, k1);
    sp2_k<<<dim3(HD / 64, 32, 4), 256, 0, stream>>>(k1, sp2w, tl, tw, offs, out);
}

// Round 2
// 1410.418 us; speedup vs baseline: 1.4124x; 1.4124x over previous
//
#include <hip/hip_runtime.h>
#include <math.h>

// ---------------- problem constants ----------------
#define T_TOK 2048
#define HD    1024
#define FD    4096
#define FH    2048     // F/2
#define HG    8192     // H * NUM_GRIDS
#define FHG   16384    // (F/2) * NUM_GRIDS
#define MAXR  4608     // max padded rows per region (4096 + 4*128 slack)

typedef __bf16 bf16x8_t __attribute__((ext_vector_type(8)));
typedef float  f32x4_t  __attribute__((ext_vector_type(4)));

// ---------------- workspace layout (bytes) ----------------
#define WS_CNT   0           // int[8]
#define WS_FILL  64          // int[8]
#define WS_OFFS  128         // int[16]: [0..7] seg start, [8..15] padded count
#define WS_SEL   256         // int[T][2]
#define WS_SELW  16640       // float[T][2]
#define WS_TL    33024       // int[2][MAXR]
#define WS_TW    69888       // float[2][MAXR]
#define WS_CTRL_END 106752
#define WS_XB    107520      // ushort[T][HD]     x bf16        (dead after fc1)
#define WS_B1    4301824     // ushort[T][HG]     rswaf(x) bf16 (dead after sp1)
#define WS_H     37856256    // ushort[MAXR][FD]  gelu(fc1)     (dead after fc2)
#define WS_B2    37856256    // ushort[MAXR][FHG] rswaf(k1) -- ALIASES hb: written in sp1 AFTER fc2 reads hb
// b2 end = 37856256 + 150994944 = 188851200  (~189 MB ws needed)

// ---------------- helpers ----------------
__device__ __forceinline__ unsigned short f2bf(float f) {
    unsigned int u = __float_as_uint(f);
    u += 0x7fffu + ((u >> 16) & 1u);   // RNE
    return (unsigned short)(u >> 16);
}
// pack two fp32 -> two bf16 (round-half-up) in ONE v_perm + 2 adds
__device__ __forceinline__ unsigned int pk2(float a, float b) {
    return __builtin_amdgcn_perm(__float_as_uint(b) + 0x8000u,
                                 __float_as_uint(a) + 0x8000u, 0x07060302u);
}
// 1 - tanh(z/2)^2 = 4 e^z / (e^z + 1)^2   (fast: v_exp + v_rcp)
__device__ __forceinline__ float rbasis(float z) {
    float u  = __expf(z);
    float t  = u + 1.0f;
    float rc = __builtin_amdgcn_rcpf(t);
    return 4.0f * u * rc * rc;
}

// ---------------- router ----------------
__global__ __launch_bounds__(256) void router_k(
    const float* __restrict__ x, const float* __restrict__ gw,
    int* __restrict__ cnt, int* __restrict__ sel, float* __restrict__ selw)
{
    const int t = blockIdx.x, tid = threadIdx.x;
    __shared__ float red[8][256];
    float p[8] = {0,0,0,0,0,0,0,0};
    for (int h = tid; h < HD; h += 256) {
        float xv = x[(size_t)t * HD + h];
        #pragma unroll
        for (int e = 0; e < 8; e++) p[e] += xv * gw[e * HD + h];
    }
    #pragma unroll
    for (int e = 0; e < 8; e++) red[e][tid] = p[e];
    __syncthreads();
    for (int s = 128; s > 0; s >>= 1) {
        if (tid < s) {
            #pragma unroll
            for (int e = 0; e < 8; e++) red[e][tid] += red[e][tid + s];
        }
        __syncthreads();
    }
    if (tid == 0) {
        float l[8];
        #pragma unroll
        for (int e = 0; e < 8; e++) l[e] = red[e][0];
        float mx = l[0];
        #pragma unroll
        for (int e = 1; e < 8; e++) mx = fmaxf(mx, l[e]);
        float pe[8];
        #pragma unroll
        for (int e = 0; e < 8; e++) pe[e] = expf(l[e] - mx);
        int i1 = 0; float v1 = pe[0];
        #pragma unroll
        for (int e = 1; e < 8; e++) if (pe[e] > v1) { v1 = pe[e]; i1 = e; }
        int i2 = -1; float v2 = -1.0f;
        #pragma unroll
        for (int e = 0; e < 8; e++) if (e != i1 && pe[e] > v2) { v2 = pe[e]; i2 = e; }
        float wsum = v1 + v2;
        sel[t * 2] = i1;  sel[t * 2 + 1] = i2;
        selw[t * 2] = v1 / wsum;  selw[t * 2 + 1] = v2 / wsum;
        atomicAdd(&cnt[i1], 1);  atomicAdd(&cnt[i2], 1);
    }
}

// ---------------- segment offsets (pad to 128 rows) ----------------
__global__ void offs_k(const int* __restrict__ cnt, int* __restrict__ offs) {
    if (threadIdx.x == 0 && blockIdx.x == 0) {
        int mo = 0;
        for (int e = 0; e < 4; e++) { offs[e] = mo; int pc = (cnt[e] + 127) & ~127; offs[8 + e] = pc; mo += pc; }
        int ko = 0;
        for (int e = 4; e < 8; e++) { offs[e] = ko; int pc = (cnt[e] + 127) & ~127; offs[8 + e] = pc; ko += pc; }
    }
}

// ---------------- build compacted token lists ----------------
__global__ __launch_bounds__(256) void build_k(
    const int* __restrict__ sel, const float* __restrict__ selw,
    const int* __restrict__ offs, int* __restrict__ fill,
    int* __restrict__ tl, float* __restrict__ tw)
{
    int t = blockIdx.x * blockDim.x + threadIdx.x;
    if (t >= T_TOK) return;
    for (int s = 0; s < 2; s++) {
        int e = sel[t * 2 + s];
        float w = selw[t * 2 + s];
        int pos = atomicAdd(&fill[e], 1);
        int r = e >> 2;
        int row = offs[e] + pos;
        tl[r * MAXR + row] = t;
        tw[r * MAXR + row] = w;
    }
}

// ---------------- xb + b1 precompute (fast basis) ----------------
__global__ __launch_bounds__(256) void basis_k(
    const float* __restrict__ x, unsigned short* __restrict__ xb,
    unsigned short* __restrict__ b1)
{
    int i = blockIdx.x * 256 + threadIdx.x;
    float v = x[i];
    xb[i] = f2bf(v);
    union { unsigned short u[8]; uint4 q; } o;
    #pragma unroll
    for (int g = 0; g < 8; g++)
        o.u[g] = f2bf(rbasis(v - (-1.2f + 0.2f * (float)g)));
    *(uint4*)(b1 + (size_t)i * 8) = o.q;
}

// ================= GEMM tiles =================
// 128x128 tile, BK=32, 4 waves in 2x2, each wave 64x64 = 4x4 mfma_16x16x32.
// LDS pitch 40 shorts (80 B, 16B-aligned, 2-way bank alias only).

#define PRO_128(PCNT_IDX, SEG_IDX)                                    \
    const int e = blockIdx.z;                                         \
    const int pcnt = offs[PCNT_IDX];                                  \
    const int mt = blockIdx.y;                                        \
    if (mt * 128 >= pcnt) return;                                     \
    const int seg = offs[SEG_IDX];                                    \
    const int tid = threadIdx.x;                                      \
    __shared__ __align__(16) unsigned short As[128 * 40];             \
    __shared__ __align__(16) unsigned short Bs[128 * 40];             \
    const int sr = tid >> 1, scol = (tid & 1) * 16;                   \
    f32x4_t acc[4][4];                                                \
    for (int i = 0; i < 4; i++)                                       \
        for (int j = 0; j < 4; j++)                                   \
            acc[i][j] = (f32x4_t){0.f, 0.f, 0.f, 0.f};                \
    const int lane = tid & 63, wv = tid >> 6;                         \
    const int wm = (wv >> 1) * 64, wn = (wv & 1) * 64;                \
    const int fr = lane & 15, quad = lane >> 4;

#define LOADA                                                         \
    uint4 av0 = *(const uint4*)(arow + kt + scol);                    \
    uint4 av1 = *(const uint4*)(arow + kt + scol + 8);

#define LOADB32                                                                      \
    float4 q0 = *(const float4*)(brow + kt + scol);                                  \
    float4 q1 = *(const float4*)(brow + kt + scol + 4);                              \
    float4 q2 = *(const float4*)(brow + kt + scol + 8);                              \
    float4 q3 = *(const float4*)(brow + kt + scol + 12);                             \
    uint4 bb0 = { pk2(q0.x,q0.y), pk2(q0.z,q0.w), pk2(q1.x,q1.y), pk2(q1.z,q1.w) };  \
    uint4 bb1 = { pk2(q2.x,q2.y), pk2(q2.z,q2.w), pk2(q3.x,q3.y), pk2(q3.z,q3.w) };

#define STEP_128                                                                     \
    __syncthreads();                                                                 \
    *(uint4*)(&As[sr * 40 + scol])     = av0;                                        \
    *(uint4*)(&As[sr * 40 + scol + 8]) = av1;                                        \
    *(uint4*)(&Bs[sr * 40 + scol])     = bb0;                                        \
    *(uint4*)(&Bs[sr * 40 + scol + 8]) = bb1;                                        \
    __syncthreads();                                                                 \
    bf16x8_t af[4], bfr[4];                                                          \
    for (int i = 0; i < 4; i++)                                                      \
        af[i] = *(const bf16x8_t*)(&As[(wm + i * 16 + fr) * 40 + quad * 8]);         \
    for (int j = 0; j < 4; j++)                                                      \
        bfr[j] = *(const bf16x8_t*)(&Bs[(wn + j * 16 + fr) * 40 + quad * 8]);        \
    for (int i = 0; i < 4; i++)                                                      \
        for (int j = 0; j < 4; j++)                                                  \
            acc[i][j] = __builtin_amdgcn_mfma_f32_16x16x32_bf16(af[i], bfr[j], acc[i][j], 0, 0, 0);

// ---- fc1: h = gelu(x @ fc1_w^T + b) -> hb ----
__global__ __launch_bounds__(256) void fc1_k(
    const unsigned short* __restrict__ xb, const float* __restrict__ w,
    const float* __restrict__ bias, const int* __restrict__ tl,
    const int* __restrict__ offs, unsigned short* __restrict__ hb)
{
    PRO_128(8 + e, e)
    const int n0 = blockIdx.x * 128;
    const int tok = tl[seg + mt * 128 + sr];
    const unsigned short* arow = xb + (size_t)tok * HD;
    const float* brow = w + (size_t)e * FD * HD + (size_t)(n0 + sr) * HD;
    for (int kt = 0; kt < HD; kt += 32) {
        LOADA
        LOADB32
        STEP_128
    }
    #pragma unroll
    for (int i = 0; i < 4; i++) {
        #pragma unroll
        for (int r = 0; r < 4; r++) {
            int m = mt * 128 + wm + i * 16 + quad * 4 + r;
            size_t rowoff = (size_t)(seg + m) * FD;
            #pragma unroll
            for (int j = 0; j < 4; j++) {
                int col = n0 + wn + j * 16 + fr;
                float v = acc[i][j][r] + bias[e * FD + col];
                float g = 0.5f * v * (1.0f + erff(v * 0.70710678118654752f));
                hb[rowoff + col] = f2bf(g);
            }
        }
    }
}

// ---- fc2: out += wt * (h @ fc2_w^T + b), K split x4 ----
__global__ __launch_bounds__(256) void fc2_k(
    const unsigned short* __restrict__ hb, const float* __restrict__ w,
    const float* __restrict__ bias, const int* __restrict__ tl,
    const float* __restrict__ tw, const int* __restrict__ offs,
    float* __restrict__ out)
{
    PRO_128(8 + e, e)
    const int nt = blockIdx.x & 7, kh = blockIdx.x >> 3;
    const int n0 = nt * 128;
    const int k0 = kh * (FD / 4);
    const unsigned short* arow = hb + (size_t)(seg + mt * 128 + sr) * FD;
    const float* brow = w + (size_t)e * HD * FD + (size_t)(n0 + sr) * FD;
    for (int kt = k0; kt < k0 + FD / 4; kt += 32) {
        LOADA
        LOADB32
        STEP_128
    }
    #pragma unroll
    for (int i = 0; i < 4; i++) {
        #pragma unroll
        for (int r = 0; r < 4; r++) {
            int rg = seg + mt * 128 + wm + i * 16 + quad * 4 + r;
            int tok = tl[rg];
            float wt = tw[rg];
            float* orow = out + (size_t)tok * HD;
            #pragma unroll
            for (int j = 0; j < 4; j++) {
                int col = n0 + wn + j * 16 + fr;
                float v = acc[i][j][r];
                if (kh == 0) v += bias[e * HD + col];
                atomicAdd(orow + col, wt * v);
            }
        }
    }
}

// ---- sp1: k1 = b1 @ sp1_w^T; epilogue expands rswaf(k1) -> b2 (bf16) ----
// 64x128 tile (M=64 for 8 m-tiles/expert => 512 active blocks)
__global__ __launch_bounds__(256) void sp1_k(
    const unsigned short* __restrict__ b1, const float* __restrict__ w,
    const int* __restrict__ tl, const int* __restrict__ offs,
    unsigned short* __restrict__ b2)
{
    const int e = blockIdx.z;
    const int pcnt = offs[12 + e];
    const int mt = blockIdx.y;
    if (mt * 64 >= pcnt) return;
    const int seg = offs[4 + e];
    const int n0 = blockIdx.x * 128;
    const int tid = threadIdx.x;
    __shared__ __align__(16) unsigned short As[64 * 40];
    __shared__ __align__(16) unsigned short Bs[128 * 40];
    const int sr = tid >> 1, scol = (tid & 1) * 16;     // B staging (128 rows)
    const int sar = tid >> 2, sac = (tid & 3) * 8;      // A staging (64 rows)
    f32x4_t acc[2][4];
    for (int i = 0; i < 2; i++)
        for (int j = 0; j < 4; j++) acc[i][j] = (f32x4_t){0.f, 0.f, 0.f, 0.f};
    const int lane = tid & 63, wv = tid >> 6;
    const int wm2 = (wv >> 1) * 32, wn = (wv & 1) * 64;
    const int fr = lane & 15, quad = lane >> 4;

    const int tok = tl[MAXR + seg + mt * 64 + sar];
    const unsigned short* arow = b1 + (size_t)tok * HG;
    const float* brow = w + (size_t)e * FH * HG + (size_t)(n0 + sr) * HG;
    for (int kt = 0; kt < HG; kt += 32) {
        uint4 av = *(const uint4*)(arow + kt + sac);
        LOADB32
        __syncthreads();
        *(uint4*)(&As[sar * 40 + sac])     = av;
        *(uint4*)(&Bs[sr * 40 + scol])     = bb0;
        *(uint4*)(&Bs[sr * 40 + scol + 8]) = bb1;
        __syncthreads();
        bf16x8_t af[2], bfr[4];
        for (int i = 0; i < 2; i++)
            af[i] = *(const bf16x8_t*)(&As[(wm2 + i * 16 + fr) * 40 + quad * 8]);
        for (int j = 0; j < 4; j++)
            bfr[j] = *(const bf16x8_t*)(&Bs[(wn + j * 16 + fr) * 40 + quad * 8]);
        for (int i = 0; i < 2; i++)
            for (int j = 0; j < 4; j++)
                acc[i][j] = __builtin_amdgcn_mfma_f32_16x16x32_bf16(af[i], bfr[j], acc[i][j], 0, 0, 0);
    }
    #pragma unroll
    for (int i = 0; i < 2; i++) {
        #pragma unroll
        for (int r = 0; r < 4; r++) {
            int m = mt * 64 + wm2 + i * 16 + quad * 4 + r;
            size_t rowoff = (size_t)(seg + m) * FHG;
            #pragma unroll
            for (int j = 0; j < 4; j++) {
                int col = n0 + wn + j * 16 + fr;
                float v = acc[i][j][r];
                union { unsigned short u[8]; uint4 q; } o;
                #pragma unroll
                for (int g = 0; g < 8; g++)
                    o.u[g] = f2bf(rbasis(v - (-1.2f + 0.2f * (float)g)));
                *(uint4*)(&b2[rowoff + (size_t)col * 8]) = o.q;
            }
        }
    }
}

// ---- sp2: out += wt * (b2 @ sp2_w^T), K split x4, pure bf16-A GEMM ----
__global__ __launch_bounds__(256) void sp2_k(
    const unsigned short* __restrict__ b2, const float* __restrict__ w,
    const int* __restrict__ tl, const float* __restrict__ tw,
    const int* __restrict__ offs, float* __restrict__ out)
{
    PRO_128(12 + e, 4 + e)
    const int nt = blockIdx.x & 7, kh = blockIdx.x >> 3;
    const int n0 = nt * 128;
    const int k0 = kh * (FHG / 4);
    const unsigned short* arow = b2 + (size_t)(seg + mt * 128 + sr) * FHG;
    const float* brow = w + (size_t)e * HD * FHG + (size_t)(n0 + sr) * FHG;
    for (int kt = k0; kt < k0 + FHG / 4; kt += 32) {
        LOADA
        LOADB32
        STEP_128
    }
    #pragma unroll
    for (int i = 0; i < 4; i++) {
        #pragma unroll
        for (int r = 0; r < 4; r++) {
            int rg = seg + mt * 128 + wm + i * 16 + quad * 4 + r;
            int tok = tl[MAXR + rg];
            float wt = tw[MAXR + rg];
            float* orow = out + (size_t)tok * HD;
            #pragma unroll
            for (int j = 0; j < 4; j++) {
                int col = n0 + wn + j * 16 + fr;
                atomicAdd(orow + col, wt * acc[i][j][r]);
            }
        }
    }
}

// ---------------- launch ----------------
extern "C" void kernel_launch(void* const* d_in, const int* in_sizes, int n_in,
                              void* d_out, int out_size, void* d_ws, size_t ws_size,
                              hipStream_t stream)
{
    const float* x    = (const float*)d_in[0];
    const float* gw   = (const float*)d_in[1];
    const float* fc1w = (const float*)d_in[2];
    const float* fc1b = (const float*)d_in[3];
    const float* fc2w = (const float*)d_in[4];
    const float* fc2b = (const float*)d_in[5];
    const float* sp1w = (const float*)d_in[6];
    const float* sp2w = (const float*)d_in[7];
    float* out = (float*)d_out;
    char* ws = (char*)d_ws;

    int*   cnt  = (int*)(ws + WS_CNT);
    int*   fill = (int*)(ws + WS_FILL);
    int*   offs = (int*)(ws + WS_OFFS);
    int*   sel  = (int*)(ws + WS_SEL);
    float* selw = (float*)(ws + WS_SELW);
    int*   tl   = (int*)(ws + WS_TL);
    float* tw   = (float*)(ws + WS_TW);
    unsigned short* xb = (unsigned short*)(ws + WS_XB);
    unsigned short* b1 = (unsigned short*)(ws + WS_B1);
    unsigned short* hb = (unsigned short*)(ws + WS_H);
    unsigned short* b2 = (unsigned short*)(ws + WS_B2);   // aliases hb (hb dead before sp1)

    hipMemsetAsync(ws, 0, WS_CTRL_END, stream);
    hipMemsetAsync(out, 0, (size_t)T_TOK * HD * sizeof(float), stream);

    router_k<<<T_TOK, 256, 0, stream>>>(x, gw, cnt, sel, selw);
    offs_k<<<1, 64, 0, stream>>>(cnt, offs);
    build_k<<<(T_TOK + 255) / 256, 256, 0, stream>>>(sel, selw, offs, fill, tl, tw);
    basis_k<<<(T_TOK * HD) / 256, 256, 0, stream>>>(x, xb, b1);

    // order matters: hb (fc1->fc2) is aliased by b2 (sp1->sp2)
    fc1_k<<<dim3(FD / 128, 16, 4), 256, 0, stream>>>(xb, fc1w, fc1b, tl, offs, hb);
    fc2_k<<<dim3((HD / 128) * 4, 16, 4), 256, 0, stream>>>(hb, fc2w, fc2b, tl, tw, offs, out);
    sp1_k<<<dim3(FH / 128, 32, 4), 256, 0, stream>>>(b1, sp1w, tl, offs, b2);
    sp2_k<<<dim3((HD / 128) * 4, 16, 4), 256, 0, stream>>>(b2, sp2w, tl, tw, offs, out);
}